// Round 22
// baseline (1444.878 us; speedup 1.0000x reference)
//
#include <hip/hip_runtime.h>
#include <math.h>

#define HW 65536
#define CPX 64     // px per conv tile
#define XSTR 136   // shorts per px row (16B-aligned stride)
#define RSTR 129   // float2 per row in half-spectrum buffer

typedef short short8 __attribute__((ext_vector_type(8)));
typedef float f32x4 __attribute__((ext_vector_type(4)));

__device__ __forceinline__ float2 cmul(float2 a, float2 b){
  return make_float2(a.x*b.x - a.y*b.y, a.x*b.y + a.y*b.x);
}

__device__ __forceinline__ unsigned short f2bf(float f){
  unsigned u = __float_as_uint(f);
  u += 0x7fff + ((u >> 16) & 1);
  return (unsigned short)(u >> 16);
}
__device__ __forceinline__ float bf2f(unsigned short h){
  unsigned u = ((unsigned)h) << 16;
  return __uint_as_float(u);
}

// ---------------- single-output conv1x1 (R11/R15-proven: ~95us) ----------------
__global__ __launch_bounds__(256,4) void conv1x1_mfma(
    const float* __restrict__ X, size_t bsX,
    const float* __restrict__ W, size_t bsW,
    float* __restrict__ Y, size_t bsY,
    const float* __restrict__ R, size_t bsR,
    int act)
{
  __shared__ __align__(16) unsigned short sbuf[2*CPX*XSTR];  // 34816 B
  unsigned short* xh = sbuf;
  unsigned short* xl = sbuf + CPX*XSTR;
  const int t = threadIdx.x;
  const int l = t & 63;
  const int w = t >> 6;
  const int b = blockIdx.z;
  const int bx = ((blockIdx.x & 7) << 7) + (blockIdx.x >> 3);   // XCD-contiguous
  const size_t pxBase = (size_t)bx * CPX;
  const float* Xb = X + (size_t)b*bsX + pxBase;
  const float* Wb = W + (size_t)b*bsW;

  short8 whi[2][4], wlo[2][4];
  {
    const int row0 = (w<<5) + (l & 15);
    const int kg = (l >> 4) << 3;
    #pragma unroll
    for (int m=0;m<2;m++){
      #pragma unroll
      for (int ks=0;ks<4;ks++){
        const float* wp = Wb + (size_t)(row0 + 16*m)*128 + 32*ks + kg;
        float4 f0 = *(const float4*)wp;
        float4 f1 = *(const float4*)(wp+4);
        float fv[8] = {f0.x,f0.y,f0.z,f0.w,f1.x,f1.y,f1.z,f1.w};
        short8 h, lo;
        #pragma unroll
        for (int e=0;e<8;e++){
          unsigned short hb = f2bf(fv[e]);
          h[e]  = (short)hb;
          lo[e] = (short)f2bf(fv[e] - bf2f(hb));
        }
        whi[m][ks]=h; wlo[m][ks]=lo;
      }
    }
  }

  {
    const int px = (t & 15) << 2;
    const int s3 = (t & 7) << 3;
    #pragma unroll
    for (int i=0;i<8;i++){
      const int k = i*16 + (t >> 4);
      float4 v = *(const float4*)(Xb + (size_t)k*HW + px);
      const int kk = k ^ s3;
      float f[4] = {v.x,v.y,v.z,v.w};
      #pragma unroll
      for (int j=0;j<4;j++){
        unsigned short hb = f2bf(f[j]);
        xh[(px+j)*XSTR + kk] = hb;
        xl[(px+j)*XSTR + kk] = f2bf(f[j] - bf2f(hb));
      }
    }
  }
  __syncthreads();

  f32x4 acc[2][4];
  #pragma unroll
  for (int m=0;m<2;m++)
    #pragma unroll
    for (int n=0;n<4;n++) acc[m][n] = (f32x4){0.f,0.f,0.f,0.f};

  const int kg = (l>>4)<<3;
  #pragma unroll
  for (int ks=0;ks<4;ks++){
    const int k0 = 32*ks + kg;
    #pragma unroll
    for (int n=0;n<4;n++){
      const int px = 16*n + (l&15);
      const int off = px*XSTR + (k0 ^ (((px>>2)&7)<<3));
      short8 bh = *(short8*)&xh[off];
      short8 bl = *(short8*)&xl[off];
      #pragma unroll
      for (int m=0;m<2;m++){
        acc[m][n] = __builtin_amdgcn_mfma_f32_16x16x32_bf16(whi[m][ks], bh, acc[m][n], 0,0,0);
        acc[m][n] = __builtin_amdgcn_mfma_f32_16x16x32_bf16(wlo[m][ks], bh, acc[m][n], 0,0,0);
        acc[m][n] = __builtin_amdgcn_mfma_f32_16x16x32_bf16(whi[m][ks], bl, acc[m][n], 0,0,0);
      }
    }
  }
  __syncthreads();

  float* ost = (float*)sbuf;
  #pragma unroll
  for (int m=0;m<2;m++){
    const int ocb = (w<<5) + 16*m + ((l>>4)<<2);
    #pragma unroll
    for (int n=0;n<4;n++){
      const int px = 16*n + (l&15);
      #pragma unroll
      for (int r=0;r<4;r++){
        float v = acc[m][n][r];
        if (act==1) v = 0.5f*v*(1.f + erff(v*0.70710678118654752440f));
        ost[(ocb+r)*68 + px] = v;
      }
    }
  }
  __syncthreads();
  float* Yb = Y + (size_t)b*bsY + pxBase;
  const float* Rb = R ? (R + (size_t)b*bsR + pxBase) : 0;
  {
    const int px4 = (t & 15) << 2;
    #pragma unroll
    for (int it=0; it<8; it++){
      const int oc = it*16 + (t >> 4);
      float4 v4 = *(float4*)&ost[oc*68 + px4];
      if (Rb){
        float4 r4 = *(const float4*)(Rb + (size_t)oc*HW + px4);
        v4.x += r4.x; v4.y += r4.y; v4.z += r4.z; v4.w += r4.w;
      }
      *(float4*)(Yb + (size_t)oc*HW + px4) = v4;
    }
  }
}

// ---------------- final conv fused with channel-LN * qf (R21-proven) ----------------
__global__ __launch_bounds__(256,4) void conv_ln_mfma(
    const float* __restrict__ Xl, const float* __restrict__ Qf,
    const float* __restrict__ lw, const float* __restrict__ lb,
    const float* __restrict__ W,
    float* __restrict__ Y, const float* __restrict__ R)
{
  __shared__ __align__(16) unsigned short sbuf[2*CPX*XSTR];  // 34816 B
  __shared__ float lnstat[2][64];
  unsigned short* xh = sbuf;
  unsigned short* xl = sbuf + CPX*XSTR;
  const int t = threadIdx.x;
  const int l = t & 63;
  const int w = t >> 6;
  const int b = blockIdx.z;
  const int bx = ((blockIdx.x & 7) << 7) + (blockIdx.x >> 3);
  const size_t pxBase = (size_t)bx * CPX;
  const size_t CBb = (size_t)b*8388608;
  const float* Xb = Xl + CBb + pxBase;
  const float* Qb = Qf + CBb + pxBase;

  const int px = (t & 15) << 2;
  const int sk = t >> 4;
  const int s3 = (t & 7) << 3;

  {
    float s1[4] = {0.f,0.f,0.f,0.f}, s2[4] = {0.f,0.f,0.f,0.f};
    #pragma unroll
    for (int i=0;i<8;i++){
      const int k = i*16 + sk;
      float4 v = *(const float4*)(Xb + (size_t)k*HW + px);
      float f[4] = {v.x,v.y,v.z,v.w};
      #pragma unroll
      for (int j=0;j<4;j++){ s1[j] += f[j]; s2[j] += f[j]*f[j]; }
    }
    float* red1 = (float*)sbuf;
    float* red2 = red1 + 1024;
    #pragma unroll
    for (int j=0;j<4;j++){ red1[sk*64 + px+j] = s1[j]; red2[sk*64 + px+j] = s2[j]; }
    __syncthreads();
    if (t < 64){
      float S1 = 0.f, S2 = 0.f;
      #pragma unroll
      for (int g=0; g<16; g++){ S1 += red1[g*64 + t]; S2 += red2[g*64 + t]; }
      float mu = S1 * (1.f/128.f);
      float var = S2 * (1.f/128.f) - mu*mu;
      lnstat[0][t] = mu;
      lnstat[1][t] = rsqrtf(var + 1e-5f);
    }
    __syncthreads();
  }

  {
    float mu[4], rs[4];
    #pragma unroll
    for (int j=0;j<4;j++){ mu[j] = lnstat[0][px+j]; rs[j] = lnstat[1][px+j]; }
    #pragma unroll
    for (int i=0;i<8;i++){
      const int k = i*16 + sk;
      float4 v = *(const float4*)(Xb + (size_t)k*HW + px);
      float4 q = *(const float4*)(Qb + (size_t)k*HW + px);
      const float lwk = lw[k], lbk = lb[k];
      const int kk = k ^ s3;
      float f[4] = {v.x,v.y,v.z,v.w};
      float qf4[4] = {q.x,q.y,q.z,q.w};
      #pragma unroll
      for (int j=0;j<4;j++){
        float val = ((f[j]-mu[j])*rs[j]*lwk + lbk) * qf4[j];
        unsigned short hb = f2bf(val);
        xh[(px+j)*XSTR + kk] = hb;
        xl[(px+j)*XSTR + kk] = f2bf(val - bf2f(hb));
      }
    }
  }

  short8 whi[2][4], wlo[2][4];
  const int kg = (l>>4)<<3;
  {
    const int row0 = (w<<5) + (l & 15);
    #pragma unroll
    for (int m=0;m<2;m++){
      #pragma unroll
      for (int ks=0;ks<4;ks++){
        const float* wp = W + (size_t)(row0 + 16*m)*128 + 32*ks + kg;
        float4 f0 = *(const float4*)wp;
        float4 f1 = *(const float4*)(wp+4);
        float fv[8] = {f0.x,f0.y,f0.z,f0.w,f1.x,f1.y,f1.z,f1.w};
        short8 h, lo;
        #pragma unroll
        for (int e=0;e<8;e++){
          unsigned short hb = f2bf(fv[e]);
          h[e]  = (short)hb;
          lo[e] = (short)f2bf(fv[e] - bf2f(hb));
        }
        whi[m][ks]=h; wlo[m][ks]=lo;
      }
    }
  }
  __syncthreads();

  f32x4 acc[2][4];
  #pragma unroll
  for (int m=0;m<2;m++)
    #pragma unroll
    for (int n=0;n<4;n++) acc[m][n] = (f32x4){0.f,0.f,0.f,0.f};
  #pragma unroll
  for (int ks=0;ks<4;ks++){
    const int k0 = 32*ks + kg;
    #pragma unroll
    for (int n=0;n<4;n++){
      const int pxr = 16*n + (l&15);
      const int off = pxr*XSTR + (k0 ^ (((pxr>>2)&7)<<3));
      short8 bh = *(short8*)&xh[off];
      short8 bl = *(short8*)&xl[off];
      #pragma unroll
      for (int m=0;m<2;m++){
        acc[m][n] = __builtin_amdgcn_mfma_f32_16x16x32_bf16(whi[m][ks], bh, acc[m][n], 0,0,0);
        acc[m][n] = __builtin_amdgcn_mfma_f32_16x16x32_bf16(wlo[m][ks], bh, acc[m][n], 0,0,0);
        acc[m][n] = __builtin_amdgcn_mfma_f32_16x16x32_bf16(whi[m][ks], bl, acc[m][n], 0,0,0);
      }
    }
  }
  __syncthreads();

  float* ost = (float*)sbuf;
  #pragma unroll
  for (int m=0;m<2;m++){
    const int ocb = (w<<5) + 16*m + ((l>>4)<<2);
    #pragma unroll
    for (int n=0;n<4;n++){
      const int pxr = 16*n + (l&15);
      #pragma unroll
      for (int r=0;r<4;r++) ost[(ocb+r)*68 + pxr] = acc[m][n][r];
    }
  }
  __syncthreads();
  float* Yb = Y + CBb + pxBase;
  const float* Rb = R + CBb + pxBase;
  {
    const int px4 = (t & 15) << 2;
    #pragma unroll
    for (int it=0; it<8; it++){
      const int oc = it*16 + (t >> 4);
      float4 v4 = *(float4*)&ost[oc*68 + px4];
      float4 r4 = *(const float4*)(Rb + (size_t)oc*HW + px4);
      v4.x += r4.x; v4.y += r4.y; v4.z += r4.z; v4.w += r4.w;
      *(float4*)(Yb + (size_t)oc*HW + px4) = v4;
    }
  }
}

// ---------------- fused gating: Y = W2 @ gelu(W1 @ X) (R17-proven) ----------------
__global__ __launch_bounds__(256,4) void conv_gate_mfma(
    const float* __restrict__ X,
    const float* __restrict__ W1, const float* __restrict__ W2,
    float* __restrict__ Y)
{
  __shared__ __align__(16) unsigned short sbuf[2*CPX*XSTR];
  unsigned short* xh = sbuf;
  unsigned short* xl = sbuf + CPX*XSTR;
  const int t = threadIdx.x;
  const int l = t & 63;
  const int w = t >> 6;
  const int b = blockIdx.z;
  const int bx = ((blockIdx.x & 7) << 7) + (blockIdx.x >> 3);
  const size_t pxBase = (size_t)bx * CPX;
  const float* Xb = X + (size_t)b*8388608 + pxBase;

  const int kg = (l>>4)<<3;
  const int row0 = (w<<5) + (l & 15);
  short8 whi[2][4], wlo[2][4];

  {
    const int px = (t & 15) << 2;
    const int s3 = (t & 7) << 3;
    #pragma unroll
    for (int i=0;i<8;i++){
      const int k = i*16 + (t >> 4);
      float4 v = *(const float4*)(Xb + (size_t)k*HW + px);
      const int kk = k ^ s3;
      float f[4] = {v.x,v.y,v.z,v.w};
      #pragma unroll
      for (int j=0;j<4;j++){
        unsigned short hb = f2bf(f[j]);
        xh[(px+j)*XSTR + kk] = hb;
        xl[(px+j)*XSTR + kk] = f2bf(f[j] - bf2f(hb));
      }
    }
  }
  #pragma unroll
  for (int m=0;m<2;m++){
    #pragma unroll
    for (int ks=0;ks<4;ks++){
      const float* wp = W1 + (size_t)(row0 + 16*m)*128 + 32*ks + kg;
      float4 f0 = *(const float4*)wp;
      float4 f1 = *(const float4*)(wp+4);
      float fv[8] = {f0.x,f0.y,f0.z,f0.w,f1.x,f1.y,f1.z,f1.w};
      short8 h, lo;
      #pragma unroll
      for (int e=0;e<8;e++){
        unsigned short hb = f2bf(fv[e]);
        h[e]  = (short)hb;
        lo[e] = (short)f2bf(fv[e] - bf2f(hb));
      }
      whi[m][ks]=h; wlo[m][ks]=lo;
    }
  }
  __syncthreads();

  f32x4 acc[2][4];
  #pragma unroll
  for (int m=0;m<2;m++)
    #pragma unroll
    for (int n=0;n<4;n++) acc[m][n] = (f32x4){0.f,0.f,0.f,0.f};
  #pragma unroll
  for (int ks=0;ks<4;ks++){
    const int k0 = 32*ks + kg;
    #pragma unroll
    for (int n=0;n<4;n++){
      const int px = 16*n + (l&15);
      const int off = px*XSTR + (k0 ^ (((px>>2)&7)<<3));
      short8 bh = *(short8*)&xh[off];
      short8 bl = *(short8*)&xl[off];
      #pragma unroll
      for (int m=0;m<2;m++){
        acc[m][n] = __builtin_amdgcn_mfma_f32_16x16x32_bf16(whi[m][ks], bh, acc[m][n], 0,0,0);
        acc[m][n] = __builtin_amdgcn_mfma_f32_16x16x32_bf16(wlo[m][ks], bh, acc[m][n], 0,0,0);
        acc[m][n] = __builtin_amdgcn_mfma_f32_16x16x32_bf16(whi[m][ks], bl, acc[m][n], 0,0,0);
      }
    }
  }
  __syncthreads();

  #pragma unroll
  for (int m=0;m<2;m++){
    const int oc0 = (w<<5) + 16*m + ((l>>4)<<2);
    #pragma unroll
    for (int n=0;n<4;n++){
      const int px = 16*n + (l&15);
      const int s3p = ((px>>2)&7)<<3;
      #pragma unroll
      for (int r=0;r<4;r++){
        float v = acc[m][n][r];
        v = 0.5f*v*(1.f + erff(v*0.70710678118654752440f));
        unsigned short hb = f2bf(v);
        const int kk = (oc0+r) ^ s3p;
        xh[px*XSTR + kk] = hb;
        xl[px*XSTR + kk] = f2bf(v - bf2f(hb));
      }
    }
  }
  #pragma unroll
  for (int m=0;m<2;m++){
    #pragma unroll
    for (int ks=0;ks<4;ks++){
      const float* wp = W2 + (size_t)(row0 + 16*m)*128 + 32*ks + kg;
      float4 f0 = *(const float4*)wp;
      float4 f1 = *(const float4*)(wp+4);
      float fv[8] = {f0.x,f0.y,f0.z,f0.w,f1.x,f1.y,f1.z,f1.w};
      short8 h, lo;
      #pragma unroll
      for (int e=0;e<8;e++){
        unsigned short hb = f2bf(fv[e]);
        h[e]  = (short)hb;
        lo[e] = (short)f2bf(fv[e] - bf2f(hb));
      }
      whi[m][ks]=h; wlo[m][ks]=lo;
    }
  }
  __syncthreads();

  #pragma unroll
  for (int m=0;m<2;m++)
    #pragma unroll
    for (int n=0;n<4;n++) acc[m][n] = (f32x4){0.f,0.f,0.f,0.f};
  #pragma unroll
  for (int ks=0;ks<4;ks++){
    const int k0 = 32*ks + kg;
    #pragma unroll
    for (int n=0;n<4;n++){
      const int px = 16*n + (l&15);
      const int off = px*XSTR + (k0 ^ (((px>>2)&7)<<3));
      short8 bh = *(short8*)&xh[off];
      short8 bl = *(short8*)&xl[off];
      #pragma unroll
      for (int m=0;m<2;m++){
        acc[m][n] = __builtin_amdgcn_mfma_f32_16x16x32_bf16(whi[m][ks], bh, acc[m][n], 0,0,0);
        acc[m][n] = __builtin_amdgcn_mfma_f32_16x16x32_bf16(wlo[m][ks], bh, acc[m][n], 0,0,0);
        acc[m][n] = __builtin_amdgcn_mfma_f32_16x16x32_bf16(whi[m][ks], bl, acc[m][n], 0,0,0);
      }
    }
  }
  __syncthreads();

  float* ost = (float*)sbuf;
  #pragma unroll
  for (int m=0;m<2;m++){
    const int ocb = (w<<5) + 16*m + ((l>>4)<<2);
    #pragma unroll
    for (int n=0;n<4;n++){
      const int px = 16*n + (l&15);
      #pragma unroll
      for (int r=0;r<4;r++) ost[(ocb+r)*68 + px] = acc[m][n][r];
    }
  }
  __syncthreads();
  float* Yb = Y + (size_t)b*8388608 + pxBase;
  {
    const int px4 = (t & 15) << 2;
    #pragma unroll
    for (int it=0; it<8; it++){
      const int oc = it*16 + (t >> 4);
      float4 v4 = *(float4*)&ost[oc*68 + px4];
      *(float4*)(Yb + (size_t)oc*HW + px4) = v4;
    }
  }
}

// ---------------- multi-output conv1x1, 16-row tbuf -> 4 blocks/CU ----------------
template<int NOUT>
__global__ __launch_bounds__(256,4) void convN_mfma(
    const float* __restrict__ X, size_t bsX,
    const float* __restrict__ W,
    float* __restrict__ Y, size_t bsY, size_t ostep)
{
  __shared__ __align__(16) unsigned short sbuf[2*CPX*XSTR];  // 34816 B (xh/xl)
  __shared__ __align__(16) float tbuf[16*68];                // 4352 B (transpose)
  unsigned short* xh = sbuf;
  unsigned short* xl = sbuf + CPX*XSTR;
  const int t = threadIdx.x;
  const int l = t & 63;
  const int w = t >> 6;
  const int b = blockIdx.z;
  const int bx = ((blockIdx.x & 7) << 7) + (blockIdx.x >> 3);
  const size_t pxBase = (size_t)bx * CPX;
  const float* Xb = X + (size_t)b*bsX + pxBase;

  {
    const int px = (t & 15) << 2;
    const int s3 = (t & 7) << 3;
    #pragma unroll
    for (int i=0;i<8;i++){
      const int k = i*16 + (t >> 4);
      float4 v = *(const float4*)(Xb + (size_t)k*HW + px);
      const int kk = k ^ s3;
      float f[4] = {v.x,v.y,v.z,v.w};
      #pragma unroll
      for (int j=0;j<4;j++){
        unsigned short hb = f2bf(f[j]);
        xh[(px+j)*XSTR + kk] = hb;
        xl[(px+j)*XSTR + kk] = f2bf(f[j] - bf2f(hb));
      }
    }
  }
  __syncthreads();

  const int kg = (l>>4)<<3;
  const int row0 = (w<<5) + (l & 15);

  #pragma unroll
  for (int o=0; o<NOUT; ++o){
    short8 whi[2][4], wlo[2][4];
    {
      const float* Wo = W + (size_t)o*16384;
      #pragma unroll
      for (int m=0;m<2;m++){
        #pragma unroll
        for (int ks=0;ks<4;ks++){
          const float* wp = Wo + (size_t)(row0 + 16*m)*128 + 32*ks + kg;
          float4 f0 = *(const float4*)wp;
          float4 f1 = *(const float4*)(wp+4);
          float fv[8] = {f0.x,f0.y,f0.z,f0.w,f1.x,f1.y,f1.z,f1.w};
          short8 h, lo;
          #pragma unroll
          for (int e=0;e<8;e++){
            unsigned short hb = f2bf(fv[e]);
            h[e]  = (short)hb;
            lo[e] = (short)f2bf(fv[e] - bf2f(hb));
          }
          whi[m][ks]=h; wlo[m][ks]=lo;
        }
      }
    }
    f32x4 acc[2][4];
    #pragma unroll
    for (int m=0;m<2;m++)
      #pragma unroll
      for (int n=0;n<4;n++) acc[m][n] = (f32x4){0.f,0.f,0.f,0.f};
    #pragma unroll
    for (int ks=0;ks<4;ks++){
      const int k0 = 32*ks + kg;
      #pragma unroll
      for (int n=0;n<4;n++){
        const int px = 16*n + (l&15);
        const int off = px*XSTR + (k0 ^ (((px>>2)&7)<<3));
        short8 bh = *(short8*)&xh[off];
        short8 bl = *(short8*)&xl[off];
        #pragma unroll
        for (int m=0;m<2;m++){
          acc[m][n] = __builtin_amdgcn_mfma_f32_16x16x32_bf16(whi[m][ks], bh, acc[m][n], 0,0,0);
          acc[m][n] = __builtin_amdgcn_mfma_f32_16x16x32_bf16(wlo[m][ks], bh, acc[m][n], 0,0,0);
          acc[m][n] = __builtin_amdgcn_mfma_f32_16x16x32_bf16(whi[m][ks], bl, acc[m][n], 0,0,0);
        }
      }
    }
    // ---- 8-chunk LDS-transposed epilogue (xh/xl preserved; 16 oc rows per chunk) ----
    float* Yb = Y + (size_t)o*ostep + (size_t)b*bsY + pxBase;
    #pragma unroll
    for (int c=0; c<8; ++c){
      __syncthreads();
      if (w == (c>>1)){
        const int m = c & 1;
        const int rbase = (l>>4)<<2;           // 0,4,8,12
        #pragma unroll
        for (int n=0;n<4;n++){
          const int px = 16*n + (l&15);
          #pragma unroll
          for (int r=0;r<4;r++) tbuf[(rbase+r)*68 + px] = acc[m][n][r];
        }
      }
      __syncthreads();
      {
        const int px4 = (t & 15) << 2;
        const int ocl = t >> 4;                 // 0..15
        float4 v4 = *(float4*)&tbuf[ocl*68 + px4];
        *(float4*)(Yb + (size_t)(16*c + ocl)*HW + px4) = v4;
      }
    }
    __syncthreads();
  }
}

// ---------------- depthwise 3x3, SAME — full-row streaming + optional sum-sq partials ----
__global__ __launch_bounds__(256,4) void dwconv3_row_k(
    const float* __restrict__ in, const float* __restrict__ w9,
    float* __restrict__ out, float* __restrict__ sqpart, int chOff)
{
  __shared__ float tl[34][256];
  int z = blockIdx.x;
  int cch = z & 127;
  int y0 = blockIdx.y * 32;
  size_t base = (size_t)z * HW;
  int t = threadIdx.x;
  float wv[9];
  #pragma unroll
  for (int i=0;i<9;i++) wv[i] = w9[cch*9+i];
  for (int idx = t; idx < 34*64; idx += 256){
    int r = idx >> 6, c4 = (idx & 63) << 2;
    int gy = y0 + r - 1;
    float4 v = make_float4(0.f,0.f,0.f,0.f);
    if ((unsigned)gy < 256u) v = *(const float4*)(in + base + (size_t)gy*256 + c4);
    *(float4*)&tl[r][c4] = v;
  }
  __syncthreads();
  const int ct = t;
  float ss = 0.f;
  for (int r = 0; r < 32; ++r){
    float acc = 0.f;
    #pragma unroll
    for (int dy=0; dy<3; dy++){
      float a  = (ct>0)   ? tl[r+dy][ct-1] : 0.f;
      float bm = tl[r+dy][ct];
      float c2 = (ct<255) ? tl[r+dy][ct+1] : 0.f;
      acc = fmaf(wv[dy*3+0], a, fmaf(wv[dy*3+1], bm, fmaf(wv[dy*3+2], c2, acc)));
    }
    out[base + (size_t)(y0+r)*256 + ct] = acc;
    ss += acc*acc;
  }
  if (sqpart){
    #pragma unroll
    for (int o=32;o>0;o>>=1) ss += __shfl_down(ss, o);
    __shared__ float red[4];
    if ((t&63)==0) red[t>>6] = ss;
    __syncthreads();
    if (t==0){
      float s = red[0]+red[1]+red[2]+red[3];
      int pg = ((z>>7)<<8) + chOff + cch;
      sqpart[pg*8 + blockIdx.y] = s;
    }
  }
}

// ---------------- partial Gram ----------------
__global__ __launch_bounds__(256) void qk_gram_k(
    const float* __restrict__ q, const float* __restrict__ k, float* __restrict__ Gp)
{
  __shared__ float qs[16][65], ks[16][65];
  int s = blockIdx.x, h = blockIdx.y, b = blockIdx.z;
  int t = threadIdx.x;
  int c = t >> 4, d = t & 15;
  const float* qb = q + ((size_t)b*128 + h*16)*HW + (size_t)s*1024;
  const float* kb = k + ((size_t)b*128 + h*16)*HW + (size_t)s*1024;
  float acc = 0.f;
  for (int n0=0;n0<1024;n0+=64){
    #pragma unroll
    for (int it=0;it<4;it++){
      int idx = it*256 + t;
      int row = idx >> 6, col = idx & 63;
      qs[row][col] = qb[(size_t)row*HW + n0 + col];
      ks[row][col] = kb[(size_t)row*HW + n0 + col];
    }
    __syncthreads();
    #pragma unroll
    for (int nn=0;nn<64;nn++) acc = fmaf(qs[c][nn], ks[d][nn], acc);
    __syncthreads();
  }
  Gp[(((size_t)b*8 + h)*64 + s)*256 + t] = acc;
}

// ---------------- combine, softmax, W_eff (fp32 out); rnorm from sqpart ----------------
__global__ __launch_bounds__(256) void attn_weff_k(
    const float* __restrict__ Gp, const float* __restrict__ sqpart,
    const float* __restrict__ temp, const float* __restrict__ proj_w,
    float* __restrict__ Weff)
{
  int b = blockIdx.x, t = threadIdx.x;
  __shared__ float G[8][16][16];
  __shared__ float A[8][16][16];
  __shared__ float rn_s[256];
  {
    const float* pp = sqpart + ((size_t)b*256 + t)*8;
    float s = 0.f;
    #pragma unroll
    for (int i=0;i<8;i++) s += pp[i];
    rn_s[t] = 1.f/fmaxf(sqrtf(s), 1e-12f);
  }
  __syncthreads();
  for (int e = t; e < 2048; e += 256){
    int h = e >> 8, cd = e & 255;
    int c = cd >> 4, d = cd & 15;
    const float* gp = Gp + (((size_t)b*8 + h)*64)*256 + cd;
    float sum = 0.f;
    for (int s2=0;s2<64;s2++) sum += gp[(size_t)s2*256];
    G[h][c][d] = sum * rn_s[h*16 + c] * rn_s[128 + h*16 + d] * temp[h];
  }
  __syncthreads();
  if (t < 128){
    int h = t >> 4, c = t & 15;
    float m = -1e30f;
    for (int d=0;d<16;d++) m = fmaxf(m, G[h][c][d]);
    float e[16], ssum = 0.f;
    for (int d=0;d<16;d++){ e[d] = expf(G[h][c][d]-m); ssum += e[d]; }
    float inv = 1.f/ssum;
    for (int d=0;d<16;d++) A[h][c][d] = e[d]*inv;
  }
  __syncthreads();
  for (int idx = t; idx < 16384; idx += 256){
    int o = idx >> 7, hd = idx & 127;
    int h = hd >> 4, d = hd & 15;
    float acc = 0.f;
    #pragma unroll
    for (int c=0;c<16;c++) acc = fmaf(proj_w[o*128 + h*16 + c], A[h][c][d], acc);
    Weff[((size_t)b*128 + o)*128 + hd] = acc;
  }
}

// ---------------- fused dwconv(kf,vf) + 8x8 circular convolution (R18/R20-proven) ----------------
__global__ __launch_bounds__(256,4) void patch_dw_circ_k(
    const float* __restrict__ kfr, const float* __restrict__ vfr,
    const float* __restrict__ dw, float* __restrict__ out)
{
  __shared__ float kraw[10*256];
  __shared__ float vraw[10*256];
  __shared__ float vs[32*68];
  __shared__ float ks2[32*68];
  int z = blockIdx.y;
  int cch = z & 127;
  int y0 = blockIdx.x * 8;
  size_t base = (size_t)z * HW;
  int t = threadIdx.x;
  float wk[9], wv2[9];
  #pragma unroll
  for (int i=0;i<9;i++){ wk[i] = dw[cch*9+i]; wv2[i] = dw[(128+cch)*9+i]; }
  for (int idx = t; idx < 10*64; idx += 256){
    int r = idx >> 6, c4 = (idx & 63) << 2;
    int gy = y0 + r - 1;
    float4 kv = make_float4(0.f,0.f,0.f,0.f), vv = kv;
    if ((unsigned)gy < 256u){
      kv = *(const float4*)(kfr + base + (size_t)gy*256 + c4);
      vv = *(const float4*)(vfr + base + (size_t)gy*256 + c4);
    }
    *(float4*)&kraw[r*256 + c4] = kv;
    *(float4*)&vraw[r*256 + c4] = vv;
  }
  __syncthreads();
  const int ct = t;
  const int pp = ct >> 3, jj = ct & 7;
  #pragma unroll
  for (int r=0;r<8;r++){
    float ak = 0.f, av = 0.f;
    #pragma unroll
    for (int dy=0;dy<3;dy++){
      float kl = (ct>0)   ? kraw[(r+dy)*256+ct-1] : 0.f;
      float km = kraw[(r+dy)*256+ct];
      float kr2= (ct<255) ? kraw[(r+dy)*256+ct+1] : 0.f;
      ak = fmaf(wk[dy*3+0],kl, fmaf(wk[dy*3+1],km, fmaf(wk[dy*3+2],kr2, ak)));
      float vl = (ct>0)   ? vraw[(r+dy)*256+ct-1] : 0.f;
      float vm = vraw[(r+dy)*256+ct];
      float vr2= (ct<255) ? vraw[(r+dy)*256+ct+1] : 0.f;
      av = fmaf(wv2[dy*3+0],vl, fmaf(wv2[dy*3+1],vm, fmaf(wv2[dy*3+2],vr2, av)));
    }
    ks2[pp*68 + r*8 + jj] = ak;
    vs [pp*68 + r*8 + jj] = av;
  }
  __syncthreads();
  int p = t & 31, pr = t >> 5;
  float acc[8];
  #pragma unroll
  for (int q=0;q<8;q++) acc[q]=0.f;
  #pragma unroll
  for (int i=0;i<8;i++){
    float4 va = *(float4*)&vs[p*68 + i*8];
    float4 vb = *(float4*)&vs[p*68 + i*8 + 4];
    int kr = (pr - i) & 7;
    float4 ka = *(float4*)&ks2[p*68 + kr*8];
    float4 kb = *(float4*)&ks2[p*68 + kr*8 + 4];
    float vv[8]={va.x,va.y,va.z,va.w,vb.x,vb.y,vb.z,vb.w};
    float kk[8]={ka.x,ka.y,ka.z,ka.w,kb.x,kb.y,kb.z,kb.w};
    #pragma unroll
    for (int q=0;q<8;q++)
      #pragma unroll
      for (int j=0;j<8;j++)
        acc[q] = fmaf(vv[j], kk[(q-j)&7], acc[q]);
  }
  float* op = out + base + (size_t)(y0+pr)*256 + p*8;
  *(float4*)op     = make_float4(acc[0],acc[1],acc[2],acc[3]);
  *(float4*)(op+4) = make_float4(acc[4],acc[5],acc[6],acc[7]);
}

// ---------------- two-for-one row FFT: rows (2r,2r+1) packed -> two half-spectra ----
__global__ __launch_bounds__(64) void fft256_rows2_r2c_half(
    const float* __restrict__ in, size_t inStride,
    float2* __restrict__ out, size_t outStride, float dir)
{
  __shared__ float2 buf[2][256];
  __shared__ float2 tw[128];
  int t = threadIdx.x;
  size_t rp = blockIdx.x;
  const float* ipa = in + (size_t)blockIdx.y*inStride + rp*512;
  const float* ipb = ipa + 256;
  float2* opa = out + (size_t)blockIdx.y*outStride + rp*2*RSTR;
  float2* opb = opa + RSTR;
  for (int i = t; i < 128; i += 64){
    float ang = 6.283185307179586477f * (float)i / 256.f;
    float s, c;
    sincosf(ang, &s, &c);
    tw[i] = make_float2(c, dir*s);
  }
  for (int i=t;i<256;i+=64) buf[0][i] = make_float2(ipa[i], ipb[i]);
  int cur = 0, m = 1;
  for (int st=0; st<8; st++){
    __syncthreads();
    #pragma unroll
    for (int p2=0;p2<2;p2++){
      int bf = t + (p2<<6);
      int k = bf & (m-1);
      int jm = bf - k;
      float2 a = buf[cur][k + jm];
      float2 c = buf[cur][k + jm + 128];
      float2 w = tw[jm];
      float2 sm = make_float2(a.x+c.x, a.y+c.y);
      float2 df = make_float2(a.x-c.x, a.y-c.y);
      buf[cur^1][k + 2*jm]     = sm;
      buf[cur^1][k + 2*jm + m] = cmul(w, df);
    }
    cur ^= 1; m <<= 1;
  }
  __syncthreads();
  for (int u=t; u<=128; u+=64){
    float2 z = buf[cur][u];
    float2 mm = buf[cur][(256-u)&255];
    opa[u] = make_float2(0.5f*(z.x+mm.x), 0.5f*(z.y-mm.y));
    opb[u] = make_float2(0.5f*(z.y+mm.y), 0.5f*(mm.x-z.x));
  }
}

// ---------------- 256-pt column FFT on half spectrum -> full real output ----------------
__global__ __launch_bounds__(256,4) void fft256_cols_c2r_herm(
    const float2* __restrict__ in, size_t inStride,
    float* __restrict__ out, size_t outStride,
    float dir, float scale)
{
  __shared__ float2 buf[16*257];
  __shared__ float2 tw[128];
  const int t = threadIdx.x;
  const int col = t & 15, rr = t >> 4;
  const int u0 = blockIdx.x << 4;
  const int u  = u0 + col;
  const int plane = blockIdx.y;
  const bool valid = (u <= 128);
  const float2* ip = in + (size_t)blockIdx.z*inStride + (size_t)plane*(256*RSTR) + u;
  if (t < 128){
    float ang = 6.283185307179586477f * (float)t / 256.f;
    float s, c;
    sincosf(ang, &s, &c);
    tw[t] = make_float2(c, dir*s);
  }
  #pragma unroll
  for (int i=0;i<16;i++){
    int r = i*16 + rr;
    float2 v = valid ? ip[(size_t)r*RSTR] : make_float2(0.f,0.f);
    int br = __brev((unsigned)r) >> 24;
    buf[col*257 + br] = v;
  }
  __syncthreads();
  for (int s=1;s<=8;s++){
    const int half = 1 << (s-1);
    const int tsh = 8 - s;
    #pragma unroll
    for (int j=0;j<8;j++){
      int bfi = rr + (j<<4);
      int lo = bfi & (half-1);
      int p  = ((bfi >> (s-1)) << s) + lo;
      float2 uq = buf[col*257 + p];
      float2 vq = buf[col*257 + p + half];
      float2 w  = tw[lo << tsh];
      float2 wv = cmul(w, vq);
      buf[col*257 + p]        = make_float2(uq.x+wv.x, uq.y+wv.y);
      buf[col*257 + p + half] = make_float2(uq.x-wv.x, uq.y-wv.y);
    }
    __syncthreads();
  }
  float* op = out + (size_t)blockIdx.z*outStride + (size_t)plane*HW;
  if (u0 < 128){
    const int c0 = (t & 3) << 2;
    #pragma unroll
    for (int i=0;i<4;i++){
      int r = i*64 + (t >> 2);
      float4 o4 = make_float4(buf[(c0+0)*257 + r].x * scale,
                              buf[(c0+1)*257 + r].x * scale,
                              buf[(c0+2)*257 + r].x * scale,
                              buf[(c0+3)*257 + r].x * scale);
      *(float4*)(op + (size_t)r*256 + u0 + c0) = o4;
    }
    const int um = u0 + col;
    if (um >= 1 && um <= 127){
      const int mc = 256 - um;
      #pragma unroll
      for (int i=0;i<16;i++){
        int r2 = i*16 + rr;
        int src = (256 - r2) & 255;
        op[(size_t)r2*256 + mc] = buf[col*257 + src].x * scale;
      }
    }
  } else {
    int r2 = t;
    op[(size_t)r2*256 + 128] = buf[0*257 + r2].x * scale;
  }
}

extern "C" void kernel_launch(void* const* d_in, const int* in_sizes, int n_in,
                              void* d_out, int out_size, void* d_ws, size_t ws_size,
                              hipStream_t stream)
{
  const float* x       = (const float*)d_in[0];
  const float* qkv_w   = (const float*)d_in[1];
  const float* qkv_dw  = (const float*)d_in[2];
  const float* proj_w  = (const float*)d_in[3];
  const float* q1_w    = (const float*)d_in[4];
  const float* q2_w    = (const float*)d_in[5];
  const float* kv_w    = (const float*)d_in[6];
  const float* kv_dw   = (const float*)d_in[7];
  const float* projf_w = (const float*)d_in[8];
  const float* temp    = (const float*)d_in[9];
  const float* ln_w    = (const float*)d_in[10];
  const float* ln_b    = (const float*)d_in[11];
  float* out = (float*)d_out;
  float* ws  = (float*)d_ws;

  const size_t P  = 33554432;      // 4*128*65536 floats
  const size_t CB = 8388608;       // per-batch stride (floats)
  const size_t HSTR = 32768u*RSTR; // per-batch half-spectrum stride (float2)
  float* A = ws;
  float* B = ws + P;
  float* C = ws + 2*P;
  float* sqpart = ws + 3*P;          // 8192
  float* Gp     = sqpart + 8192;     // 524288
  float* Weff   = Gp + 524288;       // 65536

  dim3 cg(1024,1,4); dim3 cb(256);
  dim3 dg(512,8);  dim3 db(256);

  // ---- fused qkv conv: x -> A(q_raw), B(k_raw), C(v_raw) ----
  convN_mfma<3><<<cg,cb,0,stream>>>(x, CB, qkv_w, A, CB, P);
  // ---- dw + fused sumsq ----
  dwconv3_row_k<<<dg,db,0,stream>>>(A, qkv_dw + 0*1152, out, sqpart, 0);   // q = out
  dwconv3_row_k<<<dg,db,0,stream>>>(B, qkv_dw + 1*1152, A, sqpart, 128);   // k = A
  qk_gram_k<<<dim3(64,8,4),256,0,stream>>>(out, A, Gp);
  attn_weff_k<<<4,256,0,stream>>>(Gp, sqpart, temp, proj_w, Weff);
  dwconv3_row_k<<<dg,db,0,stream>>>(C, qkv_dw + 2*1152, B, nullptr, 0);    // v = B
  // ---- attn out = Weff @ v -> C (per-batch weights) ----
  conv1x1_mfma<<<cg,cb,0,stream>>>(B, CB, Weff, 16384, C, CB, nullptr, 0, 0);
  // ---- fused kf/vf conv: C -> A(kf_raw), B(vf_raw) ----
  convN_mfma<2><<<cg,cb,0,stream>>>(C, CB, kv_w, A, CB, P);
  // ---- fused dwconv(kf,vf) + patch circular conv -> out_1 = out ----
  patch_dw_circ_k<<<dim3(32,512),256,0,stream>>>(A, B, kv_dw, out);
  // ---- forward FFT (2-for-1 rows, Hermitian cols): x -> x_fft in A; B = scratch ----
  for (int b=0;b<4;b+=2){
    fft256_rows2_r2c_half<<<dim3(16384,2),64,0,stream>>>(x + (size_t)b*CB, CB, (float2*)B, HSTR, -1.f);
    fft256_cols_c2r_herm<<<dim3(9,128,2),256,0,stream>>>((const float2*)B, HSTR, A + (size_t)b*CB, CB, -1.f, 1.f);
  }
  // ---- fused gating convs (in-place on A) ----
  conv_gate_mfma<<<cg,cb,0,stream>>>(A, q1_w, q2_w, A);
  // ---- inverse FFT: x_fft3 (A) -> qf (A); B = scratch ----
  for (int b=0;b<4;b+=2){
    fft256_rows2_r2c_half<<<dim3(16384,2),64,0,stream>>>(A + (size_t)b*CB, CB, (float2*)B, HSTR, 1.f);
    fft256_cols_c2r_herm<<<dim3(9,128,2),256,0,stream>>>((const float2*)B, HSTR, A + (size_t)b*CB, CB, 1.f, 1.f/65536.f);
  }
  // ---- final conv fused with LN(out_1=out)*qf(A), residual C -> out ----
  conv_ln_mfma<<<cg,cb,0,stream>>>(out, A, ln_w, ln_b, projf_w, out, C);
}

// Round 23
// 1402.359 us; speedup vs baseline: 1.0303x; 1.0303x over previous
//
#include <hip/hip_runtime.h>
#include <math.h>

#define HW 65536
#define CPX 64     // px per conv tile
#define XSTR 136   // shorts per px row (16B-aligned stride)
#define RSTR 129   // float2 per row in half-spectrum buffer

typedef short short8 __attribute__((ext_vector_type(8)));
typedef float f32x4 __attribute__((ext_vector_type(4)));

__device__ __forceinline__ float2 cmul(float2 a, float2 b){
  return make_float2(a.x*b.x - a.y*b.y, a.x*b.y + a.y*b.x);
}

__device__ __forceinline__ unsigned short f2bf(float f){
  unsigned u = __float_as_uint(f);
  u += 0x7fff + ((u >> 16) & 1);
  return (unsigned short)(u >> 16);
}
__device__ __forceinline__ float bf2f(unsigned short h){
  unsigned u = ((unsigned)h) << 16;
  return __uint_as_float(u);
}

// ---------------- single-output conv1x1 (R11/R15-proven: ~95us) ----------------
__global__ __launch_bounds__(256,4) void conv1x1_mfma(
    const float* __restrict__ X, size_t bsX,
    const float* __restrict__ W, size_t bsW,
    float* __restrict__ Y, size_t bsY,
    const float* __restrict__ R, size_t bsR,
    int act)
{
  __shared__ __align__(16) unsigned short sbuf[2*CPX*XSTR];  // 34816 B
  unsigned short* xh = sbuf;
  unsigned short* xl = sbuf + CPX*XSTR;
  const int t = threadIdx.x;
  const int l = t & 63;
  const int w = t >> 6;
  const int b = blockIdx.z;
  const int bx = ((blockIdx.x & 7) << 7) + (blockIdx.x >> 3);   // XCD-contiguous
  const size_t pxBase = (size_t)bx * CPX;
  const float* Xb = X + (size_t)b*bsX + pxBase;
  const float* Wb = W + (size_t)b*bsW;

  short8 whi[2][4], wlo[2][4];
  {
    const int row0 = (w<<5) + (l & 15);
    const int kg = (l >> 4) << 3;
    #pragma unroll
    for (int m=0;m<2;m++){
      #pragma unroll
      for (int ks=0;ks<4;ks++){
        const float* wp = Wb + (size_t)(row0 + 16*m)*128 + 32*ks + kg;
        float4 f0 = *(const float4*)wp;
        float4 f1 = *(const float4*)(wp+4);
        float fv[8] = {f0.x,f0.y,f0.z,f0.w,f1.x,f1.y,f1.z,f1.w};
        short8 h, lo;
        #pragma unroll
        for (int e=0;e<8;e++){
          unsigned short hb = f2bf(fv[e]);
          h[e]  = (short)hb;
          lo[e] = (short)f2bf(fv[e] - bf2f(hb));
        }
        whi[m][ks]=h; wlo[m][ks]=lo;
      }
    }
  }

  {
    const int px = (t & 15) << 2;
    const int s3 = (t & 7) << 3;
    #pragma unroll
    for (int i=0;i<8;i++){
      const int k = i*16 + (t >> 4);
      float4 v = *(const float4*)(Xb + (size_t)k*HW + px);
      const int kk = k ^ s3;
      float f[4] = {v.x,v.y,v.z,v.w};
      #pragma unroll
      for (int j=0;j<4;j++){
        unsigned short hb = f2bf(f[j]);
        xh[(px+j)*XSTR + kk] = hb;
        xl[(px+j)*XSTR + kk] = f2bf(f[j] - bf2f(hb));
      }
    }
  }
  __syncthreads();

  f32x4 acc[2][4];
  #pragma unroll
  for (int m=0;m<2;m++)
    #pragma unroll
    for (int n=0;n<4;n++) acc[m][n] = (f32x4){0.f,0.f,0.f,0.f};

  const int kg = (l>>4)<<3;
  #pragma unroll
  for (int ks=0;ks<4;ks++){
    const int k0 = 32*ks + kg;
    #pragma unroll
    for (int n=0;n<4;n++){
      const int px = 16*n + (l&15);
      const int off = px*XSTR + (k0 ^ (((px>>2)&7)<<3));
      short8 bh = *(short8*)&xh[off];
      short8 bl = *(short8*)&xl[off];
      #pragma unroll
      for (int m=0;m<2;m++){
        acc[m][n] = __builtin_amdgcn_mfma_f32_16x16x32_bf16(whi[m][ks], bh, acc[m][n], 0,0,0);
        acc[m][n] = __builtin_amdgcn_mfma_f32_16x16x32_bf16(wlo[m][ks], bh, acc[m][n], 0,0,0);
        acc[m][n] = __builtin_amdgcn_mfma_f32_16x16x32_bf16(whi[m][ks], bl, acc[m][n], 0,0,0);
      }
    }
  }
  __syncthreads();

  float* ost = (float*)sbuf;
  #pragma unroll
  for (int m=0;m<2;m++){
    const int ocb = (w<<5) + 16*m + ((l>>4)<<2);
    #pragma unroll
    for (int n=0;n<4;n++){
      const int px = 16*n + (l&15);
      #pragma unroll
      for (int r=0;r<4;r++){
        float v = acc[m][n][r];
        if (act==1) v = 0.5f*v*(1.f + erff(v*0.70710678118654752440f));
        ost[(ocb+r)*68 + px] = v;
      }
    }
  }
  __syncthreads();
  float* Yb = Y + (size_t)b*bsY + pxBase;
  const float* Rb = R ? (R + (size_t)b*bsR + pxBase) : 0;
  {
    const int px4 = (t & 15) << 2;
    #pragma unroll
    for (int it=0; it<8; it++){
      const int oc = it*16 + (t >> 4);
      float4 v4 = *(float4*)&ost[oc*68 + px4];
      if (Rb){
        float4 r4 = *(const float4*)(Rb + (size_t)oc*HW + px4);
        v4.x += r4.x; v4.y += r4.y; v4.z += r4.z; v4.w += r4.w;
      }
      *(float4*)(Yb + (size_t)oc*HW + px4) = v4;
    }
  }
}

// ---------------- final conv fused with channel-LN * qf (R21-proven) ----------------
__global__ __launch_bounds__(256,4) void conv_ln_mfma(
    const float* __restrict__ Xl, const float* __restrict__ Qf,
    const float* __restrict__ lw, const float* __restrict__ lb,
    const float* __restrict__ W,
    float* __restrict__ Y, const float* __restrict__ R)
{
  __shared__ __align__(16) unsigned short sbuf[2*CPX*XSTR];  // 34816 B
  __shared__ float lnstat[2][64];
  unsigned short* xh = sbuf;
  unsigned short* xl = sbuf + CPX*XSTR;
  const int t = threadIdx.x;
  const int l = t & 63;
  const int w = t >> 6;
  const int b = blockIdx.z;
  const int bx = ((blockIdx.x & 7) << 7) + (blockIdx.x >> 3);
  const size_t pxBase = (size_t)bx * CPX;
  const size_t CBb = (size_t)b*8388608;
  const float* Xb = Xl + CBb + pxBase;
  const float* Qb = Qf + CBb + pxBase;

  const int px = (t & 15) << 2;
  const int sk = t >> 4;
  const int s3 = (t & 7) << 3;

  {
    float s1[4] = {0.f,0.f,0.f,0.f}, s2[4] = {0.f,0.f,0.f,0.f};
    #pragma unroll
    for (int i=0;i<8;i++){
      const int k = i*16 + sk;
      float4 v = *(const float4*)(Xb + (size_t)k*HW + px);
      float f[4] = {v.x,v.y,v.z,v.w};
      #pragma unroll
      for (int j=0;j<4;j++){ s1[j] += f[j]; s2[j] += f[j]*f[j]; }
    }
    float* red1 = (float*)sbuf;
    float* red2 = red1 + 1024;
    #pragma unroll
    for (int j=0;j<4;j++){ red1[sk*64 + px+j] = s1[j]; red2[sk*64 + px+j] = s2[j]; }
    __syncthreads();
    if (t < 64){
      float S1 = 0.f, S2 = 0.f;
      #pragma unroll
      for (int g=0; g<16; g++){ S1 += red1[g*64 + t]; S2 += red2[g*64 + t]; }
      float mu = S1 * (1.f/128.f);
      float var = S2 * (1.f/128.f) - mu*mu;
      lnstat[0][t] = mu;
      lnstat[1][t] = rsqrtf(var + 1e-5f);
    }
    __syncthreads();
  }

  {
    float mu[4], rs[4];
    #pragma unroll
    for (int j=0;j<4;j++){ mu[j] = lnstat[0][px+j]; rs[j] = lnstat[1][px+j]; }
    #pragma unroll
    for (int i=0;i<8;i++){
      const int k = i*16 + sk;
      float4 v = *(const float4*)(Xb + (size_t)k*HW + px);
      float4 q = *(const float4*)(Qb + (size_t)k*HW + px);
      const float lwk = lw[k], lbk = lb[k];
      const int kk = k ^ s3;
      float f[4] = {v.x,v.y,v.z,v.w};
      float qf4[4] = {q.x,q.y,q.z,q.w};
      #pragma unroll
      for (int j=0;j<4;j++){
        float val = ((f[j]-mu[j])*rs[j]*lwk + lbk) * qf4[j];
        unsigned short hb = f2bf(val);
        xh[(px+j)*XSTR + kk] = hb;
        xl[(px+j)*XSTR + kk] = f2bf(val - bf2f(hb));
      }
    }
  }

  short8 whi[2][4], wlo[2][4];
  const int kg = (l>>4)<<3;
  {
    const int row0 = (w<<5) + (l & 15);
    #pragma unroll
    for (int m=0;m<2;m++){
      #pragma unroll
      for (int ks=0;ks<4;ks++){
        const float* wp = W + (size_t)(row0 + 16*m)*128 + 32*ks + kg;
        float4 f0 = *(const float4*)wp;
        float4 f1 = *(const float4*)(wp+4);
        float fv[8] = {f0.x,f0.y,f0.z,f0.w,f1.x,f1.y,f1.z,f1.w};
        short8 h, lo;
        #pragma unroll
        for (int e=0;e<8;e++){
          unsigned short hb = f2bf(fv[e]);
          h[e]  = (short)hb;
          lo[e] = (short)f2bf(fv[e] - bf2f(hb));
        }
        whi[m][ks]=h; wlo[m][ks]=lo;
      }
    }
  }
  __syncthreads();

  f32x4 acc[2][4];
  #pragma unroll
  for (int m=0;m<2;m++)
    #pragma unroll
    for (int n=0;n<4;n++) acc[m][n] = (f32x4){0.f,0.f,0.f,0.f};
  #pragma unroll
  for (int ks=0;ks<4;ks++){
    const int k0 = 32*ks + kg;
    #pragma unroll
    for (int n=0;n<4;n++){
      const int pxr = 16*n + (l&15);
      const int off = pxr*XSTR + (k0 ^ (((pxr>>2)&7)<<3));
      short8 bh = *(short8*)&xh[off];
      short8 bl = *(short8*)&xl[off];
      #pragma unroll
      for (int m=0;m<2;m++){
        acc[m][n] = __builtin_amdgcn_mfma_f32_16x16x32_bf16(whi[m][ks], bh, acc[m][n], 0,0,0);
        acc[m][n] = __builtin_amdgcn_mfma_f32_16x16x32_bf16(wlo[m][ks], bh, acc[m][n], 0,0,0);
        acc[m][n] = __builtin_amdgcn_mfma_f32_16x16x32_bf16(whi[m][ks], bl, acc[m][n], 0,0,0);
      }
    }
  }
  __syncthreads();

  float* ost = (float*)sbuf;
  #pragma unroll
  for (int m=0;m<2;m++){
    const int ocb = (w<<5) + 16*m + ((l>>4)<<2);
    #pragma unroll
    for (int n=0;n<4;n++){
      const int pxr = 16*n + (l&15);
      #pragma unroll
      for (int r=0;r<4;r++) ost[(ocb+r)*68 + pxr] = acc[m][n][r];
    }
  }
  __syncthreads();
  float* Yb = Y + CBb + pxBase;
  const float* Rb = R + CBb + pxBase;
  {
    const int px4 = (t & 15) << 2;
    #pragma unroll
    for (int it=0; it<8; it++){
      const int oc = it*16 + (t >> 4);
      float4 v4 = *(float4*)&ost[oc*68 + px4];
      float4 r4 = *(const float4*)(Rb + (size_t)oc*HW + px4);
      v4.x += r4.x; v4.y += r4.y; v4.z += r4.z; v4.w += r4.w;
      *(float4*)(Yb + (size_t)oc*HW + px4) = v4;
    }
  }
}

// ---------------- fused gating: Y = W2 @ gelu(W1 @ X) (R17-proven) ----------------
__global__ __launch_bounds__(256,4) void conv_gate_mfma(
    const float* __restrict__ X,
    const float* __restrict__ W1, const float* __restrict__ W2,
    float* __restrict__ Y)
{
  __shared__ __align__(16) unsigned short sbuf[2*CPX*XSTR];
  unsigned short* xh = sbuf;
  unsigned short* xl = sbuf + CPX*XSTR;
  const int t = threadIdx.x;
  const int l = t & 63;
  const int w = t >> 6;
  const int b = blockIdx.z;
  const int bx = ((blockIdx.x & 7) << 7) + (blockIdx.x >> 3);
  const size_t pxBase = (size_t)bx * CPX;
  const float* Xb = X + (size_t)b*8388608 + pxBase;

  const int kg = (l>>4)<<3;
  const int row0 = (w<<5) + (l & 15);
  short8 whi[2][4], wlo[2][4];

  {
    const int px = (t & 15) << 2;
    const int s3 = (t & 7) << 3;
    #pragma unroll
    for (int i=0;i<8;i++){
      const int k = i*16 + (t >> 4);
      float4 v = *(const float4*)(Xb + (size_t)k*HW + px);
      const int kk = k ^ s3;
      float f[4] = {v.x,v.y,v.z,v.w};
      #pragma unroll
      for (int j=0;j<4;j++){
        unsigned short hb = f2bf(f[j]);
        xh[(px+j)*XSTR + kk] = hb;
        xl[(px+j)*XSTR + kk] = f2bf(f[j] - bf2f(hb));
      }
    }
  }
  #pragma unroll
  for (int m=0;m<2;m++){
    #pragma unroll
    for (int ks=0;ks<4;ks++){
      const float* wp = W1 + (size_t)(row0 + 16*m)*128 + 32*ks + kg;
      float4 f0 = *(const float4*)wp;
      float4 f1 = *(const float4*)(wp+4);
      float fv[8] = {f0.x,f0.y,f0.z,f0.w,f1.x,f1.y,f1.z,f1.w};
      short8 h, lo;
      #pragma unroll
      for (int e=0;e<8;e++){
        unsigned short hb = f2bf(fv[e]);
        h[e]  = (short)hb;
        lo[e] = (short)f2bf(fv[e] - bf2f(hb));
      }
      whi[m][ks]=h; wlo[m][ks]=lo;
    }
  }
  __syncthreads();

  f32x4 acc[2][4];
  #pragma unroll
  for (int m=0;m<2;m++)
    #pragma unroll
    for (int n=0;n<4;n++) acc[m][n] = (f32x4){0.f,0.f,0.f,0.f};
  #pragma unroll
  for (int ks=0;ks<4;ks++){
    const int k0 = 32*ks + kg;
    #pragma unroll
    for (int n=0;n<4;n++){
      const int px = 16*n + (l&15);
      const int off = px*XSTR + (k0 ^ (((px>>2)&7)<<3));
      short8 bh = *(short8*)&xh[off];
      short8 bl = *(short8*)&xl[off];
      #pragma unroll
      for (int m=0;m<2;m++){
        acc[m][n] = __builtin_amdgcn_mfma_f32_16x16x32_bf16(whi[m][ks], bh, acc[m][n], 0,0,0);
        acc[m][n] = __builtin_amdgcn_mfma_f32_16x16x32_bf16(wlo[m][ks], bh, acc[m][n], 0,0,0);
        acc[m][n] = __builtin_amdgcn_mfma_f32_16x16x32_bf16(whi[m][ks], bl, acc[m][n], 0,0,0);
      }
    }
  }
  __syncthreads();

  #pragma unroll
  for (int m=0;m<2;m++){
    const int oc0 = (w<<5) + 16*m + ((l>>4)<<2);
    #pragma unroll
    for (int n=0;n<4;n++){
      const int px = 16*n + (l&15);
      const int s3p = ((px>>2)&7)<<3;
      #pragma unroll
      for (int r=0;r<4;r++){
        float v = acc[m][n][r];
        v = 0.5f*v*(1.f + erff(v*0.70710678118654752440f));
        unsigned short hb = f2bf(v);
        const int kk = (oc0+r) ^ s3p;
        xh[px*XSTR + kk] = hb;
        xl[px*XSTR + kk] = f2bf(v - bf2f(hb));
      }
    }
  }
  #pragma unroll
  for (int m=0;m<2;m++){
    #pragma unroll
    for (int ks=0;ks<4;ks++){
      const float* wp = W2 + (size_t)(row0 + 16*m)*128 + 32*ks + kg;
      float4 f0 = *(const float4*)wp;
      float4 f1 = *(const float4*)(wp+4);
      float fv[8] = {f0.x,f0.y,f0.z,f0.w,f1.x,f1.y,f1.z,f1.w};
      short8 h, lo;
      #pragma unroll
      for (int e=0;e<8;e++){
        unsigned short hb = f2bf(fv[e]);
        h[e]  = (short)hb;
        lo[e] = (short)f2bf(fv[e] - bf2f(hb));
      }
      whi[m][ks]=h; wlo[m][ks]=lo;
    }
  }
  __syncthreads();

  #pragma unroll
  for (int m=0;m<2;m++)
    #pragma unroll
    for (int n=0;n<4;n++) acc[m][n] = (f32x4){0.f,0.f,0.f,0.f};
  #pragma unroll
  for (int ks=0;ks<4;ks++){
    const int k0 = 32*ks + kg;
    #pragma unroll
    for (int n=0;n<4;n++){
      const int px = 16*n + (l&15);
      const int off = px*XSTR + (k0 ^ (((px>>2)&7)<<3));
      short8 bh = *(short8*)&xh[off];
      short8 bl = *(short8*)&xl[off];
      #pragma unroll
      for (int m=0;m<2;m++){
        acc[m][n] = __builtin_amdgcn_mfma_f32_16x16x32_bf16(whi[m][ks], bh, acc[m][n], 0,0,0);
        acc[m][n] = __builtin_amdgcn_mfma_f32_16x16x32_bf16(wlo[m][ks], bh, acc[m][n], 0,0,0);
        acc[m][n] = __builtin_amdgcn_mfma_f32_16x16x32_bf16(whi[m][ks], bl, acc[m][n], 0,0,0);
      }
    }
  }
  __syncthreads();

  float* ost = (float*)sbuf;
  #pragma unroll
  for (int m=0;m<2;m++){
    const int ocb = (w<<5) + 16*m + ((l>>4)<<2);
    #pragma unroll
    for (int n=0;n<4;n++){
      const int px = 16*n + (l&15);
      #pragma unroll
      for (int r=0;r<4;r++) ost[(ocb+r)*68 + px] = acc[m][n][r];
    }
  }
  __syncthreads();
  float* Yb = Y + (size_t)b*8388608 + pxBase;
  {
    const int px4 = (t & 15) << 2;
    #pragma unroll
    for (int it=0; it<8; it++){
      const int oc = it*16 + (t >> 4);
      float4 v4 = *(float4*)&ost[oc*68 + px4];
      *(float4*)(Yb + (size_t)oc*HW + px4) = v4;
    }
  }
}

// ---------------- multi-output conv1x1 (R16-proven: 64-row tbuf, 3 blocks/CU) ----------------
template<int NOUT>
__global__ __launch_bounds__(256,3) void convN_mfma(
    const float* __restrict__ X, size_t bsX,
    const float* __restrict__ W,
    float* __restrict__ Y, size_t bsY, size_t ostep)
{
  __shared__ __align__(16) unsigned short sbuf[2*CPX*XSTR];  // 34816 B (xh/xl)
  __shared__ __align__(16) float tbuf[64*68];                // 17408 B (transpose)
  unsigned short* xh = sbuf;
  unsigned short* xl = sbuf + CPX*XSTR;
  const int t = threadIdx.x;
  const int l = t & 63;
  const int w = t >> 6;
  const int b = blockIdx.z;
  const int bx = ((blockIdx.x & 7) << 7) + (blockIdx.x >> 3);
  const size_t pxBase = (size_t)bx * CPX;
  const float* Xb = X + (size_t)b*bsX + pxBase;

  {
    const int px = (t & 15) << 2;
    const int s3 = (t & 7) << 3;
    #pragma unroll
    for (int i=0;i<8;i++){
      const int k = i*16 + (t >> 4);
      float4 v = *(const float4*)(Xb + (size_t)k*HW + px);
      const int kk = k ^ s3;
      float f[4] = {v.x,v.y,v.z,v.w};
      #pragma unroll
      for (int j=0;j<4;j++){
        unsigned short hb = f2bf(f[j]);
        xh[(px+j)*XSTR + kk] = hb;
        xl[(px+j)*XSTR + kk] = f2bf(f[j] - bf2f(hb));
      }
    }
  }
  __syncthreads();

  const int kg = (l>>4)<<3;
  const int row0 = (w<<5) + (l & 15);

  #pragma unroll
  for (int o=0; o<NOUT; ++o){
    short8 whi[2][4], wlo[2][4];
    {
      const float* Wo = W + (size_t)o*16384;
      #pragma unroll
      for (int m=0;m<2;m++){
        #pragma unroll
        for (int ks=0;ks<4;ks++){
          const float* wp = Wo + (size_t)(row0 + 16*m)*128 + 32*ks + kg;
          float4 f0 = *(const float4*)wp;
          float4 f1 = *(const float4*)(wp+4);
          float fv[8] = {f0.x,f0.y,f0.z,f0.w,f1.x,f1.y,f1.z,f1.w};
          short8 h, lo;
          #pragma unroll
          for (int e=0;e<8;e++){
            unsigned short hb = f2bf(fv[e]);
            h[e]  = (short)hb;
            lo[e] = (short)f2bf(fv[e] - bf2f(hb));
          }
          whi[m][ks]=h; wlo[m][ks]=lo;
        }
      }
    }
    f32x4 acc[2][4];
    #pragma unroll
    for (int m=0;m<2;m++)
      #pragma unroll
      for (int n=0;n<4;n++) acc[m][n] = (f32x4){0.f,0.f,0.f,0.f};
    #pragma unroll
    for (int ks=0;ks<4;ks++){
      const int k0 = 32*ks + kg;
      #pragma unroll
      for (int n=0;n<4;n++){
        const int px = 16*n + (l&15);
        const int off = px*XSTR + (k0 ^ (((px>>2)&7)<<3));
        short8 bh = *(short8*)&xh[off];
        short8 bl = *(short8*)&xl[off];
        #pragma unroll
        for (int m=0;m<2;m++){
          acc[m][n] = __builtin_amdgcn_mfma_f32_16x16x32_bf16(whi[m][ks], bh, acc[m][n], 0,0,0);
          acc[m][n] = __builtin_amdgcn_mfma_f32_16x16x32_bf16(wlo[m][ks], bh, acc[m][n], 0,0,0);
          acc[m][n] = __builtin_amdgcn_mfma_f32_16x16x32_bf16(whi[m][ks], bl, acc[m][n], 0,0,0);
        }
      }
    }
    float* Yb = Y + (size_t)o*ostep + (size_t)b*bsY + pxBase;
    #pragma unroll
    for (int half=0; half<2; ++half){
      __syncthreads();
      if ((w >> 1) == half){
        #pragma unroll
        for (int m=0;m<2;m++){
          const int ocl = ((w&1)<<5) + 16*m + ((l>>4)<<2);
          #pragma unroll
          for (int n=0;n<4;n++){
            const int px = 16*n + (l&15);
            #pragma unroll
            for (int r=0;r<4;r++) tbuf[(ocl+r)*68 + px] = acc[m][n][r];
          }
        }
      }
      __syncthreads();
      {
        const int px4 = (t & 15) << 2;
        #pragma unroll
        for (int it=0; it<4; it++){
          const int ocl = it*16 + (t >> 4);
          float4 v4 = *(float4*)&tbuf[ocl*68 + px4];
          *(float4*)(Yb + (size_t)(64*half + ocl)*HW + px4) = v4;
        }
      }
    }
    __syncthreads();
  }
}

// ---------------- depthwise 3x3, SAME — full-row streaming + optional sum-sq partials ----
__global__ __launch_bounds__(256,4) void dwconv3_row_k(
    const float* __restrict__ in, const float* __restrict__ w9,
    float* __restrict__ out, float* __restrict__ sqpart, int chOff)
{
  __shared__ float tl[34][256];
  int z = blockIdx.x;
  int cch = z & 127;
  int y0 = blockIdx.y * 32;
  size_t base = (size_t)z * HW;
  int t = threadIdx.x;
  float wv[9];
  #pragma unroll
  for (int i=0;i<9;i++) wv[i] = w9[cch*9+i];
  for (int idx = t; idx < 34*64; idx += 256){
    int r = idx >> 6, c4 = (idx & 63) << 2;
    int gy = y0 + r - 1;
    float4 v = make_float4(0.f,0.f,0.f,0.f);
    if ((unsigned)gy < 256u) v = *(const float4*)(in + base + (size_t)gy*256 + c4);
    *(float4*)&tl[r][c4] = v;
  }
  __syncthreads();
  const int ct = t;
  float ss = 0.f;
  for (int r = 0; r < 32; ++r){
    float acc = 0.f;
    #pragma unroll
    for (int dy=0; dy<3; dy++){
      float a  = (ct>0)   ? tl[r+dy][ct-1] : 0.f;
      float bm = tl[r+dy][ct];
      float c2 = (ct<255) ? tl[r+dy][ct+1] : 0.f;
      acc = fmaf(wv[dy*3+0], a, fmaf(wv[dy*3+1], bm, fmaf(wv[dy*3+2], c2, acc)));
    }
    out[base + (size_t)(y0+r)*256 + ct] = acc;
    ss += acc*acc;
  }
  if (sqpart){
    #pragma unroll
    for (int o=32;o>0;o>>=1) ss += __shfl_down(ss, o);
    __shared__ float red[4];
    if ((t&63)==0) red[t>>6] = ss;
    __syncthreads();
    if (t==0){
      float s = red[0]+red[1]+red[2]+red[3];
      int pg = ((z>>7)<<8) + chOff + cch;
      sqpart[pg*8 + blockIdx.y] = s;
    }
  }
}

// ---------------- partial Gram ----------------
__global__ __launch_bounds__(256) void qk_gram_k(
    const float* __restrict__ q, const float* __restrict__ k, float* __restrict__ Gp)
{
  __shared__ float qs[16][65], ks[16][65];
  int s = blockIdx.x, h = blockIdx.y, b = blockIdx.z;
  int t = threadIdx.x;
  int c = t >> 4, d = t & 15;
  const float* qb = q + ((size_t)b*128 + h*16)*HW + (size_t)s*1024;
  const float* kb = k + ((size_t)b*128 + h*16)*HW + (size_t)s*1024;
  float acc = 0.f;
  for (int n0=0;n0<1024;n0+=64){
    #pragma unroll
    for (int it=0;it<4;it++){
      int idx = it*256 + t;
      int row = idx >> 6, col = idx & 63;
      qs[row][col] = qb[(size_t)row*HW + n0 + col];
      ks[row][col] = kb[(size_t)row*HW + n0 + col];
    }
    __syncthreads();
    #pragma unroll
    for (int nn=0;nn<64;nn++) acc = fmaf(qs[c][nn], ks[d][nn], acc);
    __syncthreads();
  }
  Gp[(((size_t)b*8 + h)*64 + s)*256 + t] = acc;
}

// ---------------- combine, softmax, W_eff (fp32 out); rnorm from sqpart ----------------
__global__ __launch_bounds__(256) void attn_weff_k(
    const float* __restrict__ Gp, const float* __restrict__ sqpart,
    const float* __restrict__ temp, const float* __restrict__ proj_w,
    float* __restrict__ Weff)
{
  int b = blockIdx.x, t = threadIdx.x;
  __shared__ float G[8][16][16];
  __shared__ float A[8][16][16];
  __shared__ float rn_s[256];
  {
    const float* pp = sqpart + ((size_t)b*256 + t)*8;
    float s = 0.f;
    #pragma unroll
    for (int i=0;i<8;i++) s += pp[i];
    rn_s[t] = 1.f/fmaxf(sqrtf(s), 1e-12f);
  }
  __syncthreads();
  for (int e = t; e < 2048; e += 256){
    int h = e >> 8, cd = e & 255;
    int c = cd >> 4, d = cd & 15;
    const float* gp = Gp + (((size_t)b*8 + h)*64)*256 + cd;
    float sum = 0.f;
    for (int s2=0;s2<64;s2++) sum += gp[(size_t)s2*256];
    G[h][c][d] = sum * rn_s[h*16 + c] * rn_s[128 + h*16 + d] * temp[h];
  }
  __syncthreads();
  if (t < 128){
    int h = t >> 4, c = t & 15;
    float m = -1e30f;
    for (int d=0;d<16;d++) m = fmaxf(m, G[h][c][d]);
    float e[16], ssum = 0.f;
    for (int d=0;d<16;d++){ e[d] = expf(G[h][c][d]-m); ssum += e[d]; }
    float inv = 1.f/ssum;
    for (int d=0;d<16;d++) A[h][c][d] = e[d]*inv;
  }
  __syncthreads();
  for (int idx = t; idx < 16384; idx += 256){
    int o = idx >> 7, hd = idx & 127;
    int h = hd >> 4, d = hd & 15;
    float acc = 0.f;
    #pragma unroll
    for (int c=0;c<16;c++) acc = fmaf(proj_w[o*128 + h*16 + c], A[h][c][d], acc);
    Weff[((size_t)b*128 + o)*128 + hd] = acc;
  }
}

// ---------------- fused dwconv(kf,vf) + 8x8 circular convolution (R18/R20-proven) ----------------
__global__ __launch_bounds__(256,4) void patch_dw_circ_k(
    const float* __restrict__ kfr, const float* __restrict__ vfr,
    const float* __restrict__ dw, float* __restrict__ out)
{
  __shared__ float kraw[10*256];
  __shared__ float vraw[10*256];
  __shared__ float vs[32*68];
  __shared__ float ks2[32*68];
  int z = blockIdx.y;
  int cch = z & 127;
  int y0 = blockIdx.x * 8;
  size_t base = (size_t)z * HW;
  int t = threadIdx.x;
  float wk[9], wv2[9];
  #pragma unroll
  for (int i=0;i<9;i++){ wk[i] = dw[cch*9+i]; wv2[i] = dw[(128+cch)*9+i]; }
  for (int idx = t; idx < 10*64; idx += 256){
    int r = idx >> 6, c4 = (idx & 63) << 2;
    int gy = y0 + r - 1;
    float4 kv = make_float4(0.f,0.f,0.f,0.f), vv = kv;
    if ((unsigned)gy < 256u){
      kv = *(const float4*)(kfr + base + (size_t)gy*256 + c4);
      vv = *(const float4*)(vfr + base + (size_t)gy*256 + c4);
    }
    *(float4*)&kraw[r*256 + c4] = kv;
    *(float4*)&vraw[r*256 + c4] = vv;
  }
  __syncthreads();
  const int ct = t;
  const int pp = ct >> 3, jj = ct & 7;
  #pragma unroll
  for (int r=0;r<8;r++){
    float ak = 0.f, av = 0.f;
    #pragma unroll
    for (int dy=0;dy<3;dy++){
      float kl = (ct>0)   ? kraw[(r+dy)*256+ct-1] : 0.f;
      float km = kraw[(r+dy)*256+ct];
      float kr2= (ct<255) ? kraw[(r+dy)*256+ct+1] : 0.f;
      ak = fmaf(wk[dy*3+0],kl, fmaf(wk[dy*3+1],km, fmaf(wk[dy*3+2],kr2, ak)));
      float vl = (ct>0)   ? vraw[(r+dy)*256+ct-1] : 0.f;
      float vm = vraw[(r+dy)*256+ct];
      float vr2= (ct<255) ? vraw[(r+dy)*256+ct+1] : 0.f;
      av = fmaf(wv2[dy*3+0],vl, fmaf(wv2[dy*3+1],vm, fmaf(wv2[dy*3+2],vr2, av)));
    }
    ks2[pp*68 + r*8 + jj] = ak;
    vs [pp*68 + r*8 + jj] = av;
  }
  __syncthreads();
  int p = t & 31, pr = t >> 5;
  float acc[8];
  #pragma unroll
  for (int q=0;q<8;q++) acc[q]=0.f;
  #pragma unroll
  for (int i=0;i<8;i++){
    float4 va = *(float4*)&vs[p*68 + i*8];
    float4 vb = *(float4*)&vs[p*68 + i*8 + 4];
    int kr = (pr - i) & 7;
    float4 ka = *(float4*)&ks2[p*68 + kr*8];
    float4 kb = *(float4*)&ks2[p*68 + kr*8 + 4];
    float vv[8]={va.x,va.y,va.z,va.w,vb.x,vb.y,vb.z,vb.w};
    float kk[8]={ka.x,ka.y,ka.z,ka.w,kb.x,kb.y,kb.z,kb.w};
    #pragma unroll
    for (int q=0;q<8;q++)
      #pragma unroll
      for (int j=0;j<8;j++)
        acc[q] = fmaf(vv[j], kk[(q-j)&7], acc[q]);
  }
  float* op = out + base + (size_t)(y0+pr)*256 + p*8;
  *(float4*)op     = make_float4(acc[0],acc[1],acc[2],acc[3]);
  *(float4*)(op+4) = make_float4(acc[4],acc[5],acc[6],acc[7]);
}

// ---------------- two-for-one row FFT: rows (2r,2r+1) packed -> two half-spectra ----
__global__ __launch_bounds__(64) void fft256_rows2_r2c_half(
    const float* __restrict__ in, size_t inStride,
    float2* __restrict__ out, size_t outStride, float dir)
{
  __shared__ float2 buf[2][256];
  __shared__ float2 tw[128];
  int t = threadIdx.x;
  size_t rp = blockIdx.x;
  const float* ipa = in + (size_t)blockIdx.y*inStride + rp*512;
  const float* ipb = ipa + 256;
  float2* opa = out + (size_t)blockIdx.y*outStride + rp*2*RSTR;
  float2* opb = opa + RSTR;
  for (int i = t; i < 128; i += 64){
    float ang = 6.283185307179586477f * (float)i / 256.f;
    float s, c;
    sincosf(ang, &s, &c);
    tw[i] = make_float2(c, dir*s);
  }
  for (int i=t;i<256;i+=64) buf[0][i] = make_float2(ipa[i], ipb[i]);
  int cur = 0, m = 1;
  for (int st=0; st<8; st++){
    __syncthreads();
    #pragma unroll
    for (int p2=0;p2<2;p2++){
      int bf = t + (p2<<6);
      int k = bf & (m-1);
      int jm = bf - k;
      float2 a = buf[cur][k + jm];
      float2 c = buf[cur][k + jm + 128];
      float2 w = tw[jm];
      float2 sm = make_float2(a.x+c.x, a.y+c.y);
      float2 df = make_float2(a.x-c.x, a.y-c.y);
      buf[cur^1][k + 2*jm]     = sm;
      buf[cur^1][k + 2*jm + m] = cmul(w, df);
    }
    cur ^= 1; m <<= 1;
  }
  __syncthreads();
  for (int u=t; u<=128; u+=64){
    float2 z = buf[cur][u];
    float2 mm = buf[cur][(256-u)&255];
    opa[u] = make_float2(0.5f*(z.x+mm.x), 0.5f*(z.y-mm.y));
    opb[u] = make_float2(0.5f*(z.y+mm.y), 0.5f*(mm.x-z.x));
  }
}

// ---------------- 256-pt column FFT on half spectrum -> full real output ----------------
__global__ __launch_bounds__(256,4) void fft256_cols_c2r_herm(
    const float2* __restrict__ in, size_t inStride,
    float* __restrict__ out, size_t outStride,
    float dir, float scale)
{
  __shared__ float2 buf[16*257];
  __shared__ float2 tw[128];
  const int t = threadIdx.x;
  const int col = t & 15, rr = t >> 4;
  const int u0 = blockIdx.x << 4;
  const int u  = u0 + col;
  const int plane = blockIdx.y;
  const bool valid = (u <= 128);
  const float2* ip = in + (size_t)blockIdx.z*inStride + (size_t)plane*(256*RSTR) + u;
  if (t < 128){
    float ang = 6.283185307179586477f * (float)t / 256.f;
    float s, c;
    sincosf(ang, &s, &c);
    tw[t] = make_float2(c, dir*s);
  }
  #pragma unroll
  for (int i=0;i<16;i++){
    int r = i*16 + rr;
    float2 v = valid ? ip[(size_t)r*RSTR] : make_float2(0.f,0.f);
    int br = __brev((unsigned)r) >> 24;
    buf[col*257 + br] = v;
  }
  __syncthreads();
  for (int s=1;s<=8;s++){
    const int half = 1 << (s-1);
    const int tsh = 8 - s;
    #pragma unroll
    for (int j=0;j<8;j++){
      int bfi = rr + (j<<4);
      int lo = bfi & (half-1);
      int p  = ((bfi >> (s-1)) << s) + lo;
      float2 uq = buf[col*257 + p];
      float2 vq = buf[col*257 + p + half];
      float2 w  = tw[lo << tsh];
      float2 wv = cmul(w, vq);
      buf[col*257 + p]        = make_float2(uq.x+wv.x, uq.y+wv.y);
      buf[col*257 + p + half] = make_float2(uq.x-wv.x, uq.y-wv.y);
    }
    __syncthreads();
  }
  float* op = out + (size_t)blockIdx.z*outStride + (size_t)plane*HW;
  if (u0 < 128){
    const int c0 = (t & 3) << 2;
    #pragma unroll
    for (int i=0;i<4;i++){
      int r = i*64 + (t >> 2);
      float4 o4 = make_float4(buf[(c0+0)*257 + r].x * scale,
                              buf[(c0+1)*257 + r].x * scale,
                              buf[(c0+2)*257 + r].x * scale,
                              buf[(c0+3)*257 + r].x * scale);
      *(float4*)(op + (size_t)r*256 + u0 + c0) = o4;
    }
    const int um = u0 + col;
    if (um >= 1 && um <= 127){
      const int mc = 256 - um;
      #pragma unroll
      for (int i=0;i<16;i++){
        int r2 = i*16 + rr;
        int src = (256 - r2) & 255;
        op[(size_t)r2*256 + mc] = buf[col*257 + src].x * scale;
      }
    }
  } else {
    int r2 = t;
    op[(size_t)r2*256 + 128] = buf[0*257 + r2].x * scale;
  }
}

extern "C" void kernel_launch(void* const* d_in, const int* in_sizes, int n_in,
                              void* d_out, int out_size, void* d_ws, size_t ws_size,
                              hipStream_t stream)
{
  const float* x       = (const float*)d_in[0];
  const float* qkv_w   = (const float*)d_in[1];
  const float* qkv_dw  = (const float*)d_in[2];
  const float* proj_w  = (const float*)d_in[3];
  const float* q1_w    = (const float*)d_in[4];
  const float* q2_w    = (const float*)d_in[5];
  const float* kv_w    = (const float*)d_in[6];
  const float* kv_dw   = (const float*)d_in[7];
  const float* projf_w = (const float*)d_in[8];
  const float* temp    = (const float*)d_in[9];
  const float* ln_w    = (const float*)d_in[10];
  const float* ln_b    = (const float*)d_in[11];
  float* out = (float*)d_out;
  float* ws  = (float*)d_ws;

  const size_t P  = 33554432;      // 4*128*65536 floats
  const size_t CB = 8388608;       // per-batch stride (floats)
  const size_t HSTR = 32768u*RSTR; // per-batch half-spectrum stride (float2)
  float* A = ws;
  float* B = ws + P;
  float* C = ws + 2*P;
  float* sqpart = ws + 3*P;          // 8192
  float* Gp     = sqpart + 8192;     // 524288
  float* Weff   = Gp + 524288;       // 65536

  dim3 cg(1024,1,4); dim3 cb(256);
  dim3 dg(512,8);  dim3 db(256);

  // ---- fused qkv conv: x -> A(q_raw), B(k_raw), C(v_raw) ----
  convN_mfma<3><<<cg,cb,0,stream>>>(x, CB, qkv_w, A, CB, P);
  // ---- dw + fused sumsq ----
  dwconv3_row_k<<<dg,db,0,stream>>>(A, qkv_dw + 0*1152, out, sqpart, 0);   // q = out
  dwconv3_row_k<<<dg,db,0,stream>>>(B, qkv_dw + 1*1152, A, sqpart, 128);   // k = A
  qk_gram_k<<<dim3(64,8,4),256,0,stream>>>(out, A, Gp);
  attn_weff_k<<<4,256,0,stream>>>(Gp, sqpart, temp, proj_w, Weff);
  dwconv3_row_k<<<dg,db,0,stream>>>(C, qkv_dw + 2*1152, B, nullptr, 0);    // v = B
  // ---- attn out = Weff @ v -> C (per-batch weights) ----
  conv1x1_mfma<<<cg,cb,0,stream>>>(B, CB, Weff, 16384, C, CB, nullptr, 0, 0);
  // ---- fused kf/vf conv: C -> A(kf_raw), B(vf_raw) ----
  convN_mfma<2><<<cg,cb,0,stream>>>(C, CB, kv_w, A, CB, P);
  // ---- fused dwconv(kf,vf) + patch circular conv -> out_1 = out ----
  patch_dw_circ_k<<<dim3(32,512),256,0,stream>>>(A, B, kv_dw, out);
  // ---- forward FFT (2-for-1 rows, Hermitian cols): x -> x_fft in A; B = scratch ----
  for (int b=0;b<4;b+=2){
    fft256_rows2_r2c_half<<<dim3(16384,2),64,0,stream>>>(x + (size_t)b*CB, CB, (float2*)B, HSTR, -1.f);
    fft256_cols_c2r_herm<<<dim3(9,128,2),256,0,stream>>>((const float2*)B, HSTR, A + (size_t)b*CB, CB, -1.f, 1.f);
  }
  // ---- fused gating convs (in-place on A) ----
  conv_gate_mfma<<<cg,cb,0,stream>>>(A, q1_w, q2_w, A);
  // ---- inverse FFT: x_fft3 (A) -> qf (A); B = scratch ----
  for (int b=0;b<4;b+=2){
    fft256_rows2_r2c_half<<<dim3(16384,2),64,0,stream>>>(A + (size_t)b*CB, CB, (float2*)B, HSTR, 1.f);
    fft256_cols_c2r_herm<<<dim3(9,128,2),256,0,stream>>>((const float2*)B, HSTR, A + (size_t)b*CB, CB, 1.f, 1.f/65536.f);
  }
  // ---- final conv fused with LN(out_1=out)*qf(A), residual C -> out ----
  conv_ln_mfma<<<cg,cb,0,stream>>>(out, A, ln_w, ln_b, projf_w, out, C);
}